// Round 2
// baseline (4486.823 us; speedup 1.0000x reference)
//
#include <hip/hip_runtime.h>
#include <hip/hip_bf16.h>
#include <stdint.h>

#define D_MODEL 2048
#define D_FF    8192
#define NTOK    4096
#define WSCALE  0.02f

using bf16 = __hip_bfloat16;
typedef __bf16 bf16x8 __attribute__((ext_vector_type(8)));
typedef float  f32x4  __attribute__((ext_vector_type(4)));

// async global -> LDS, 16 B per lane (wave-uniform base + lane*16 layout)
__device__ __forceinline__ void gld_lds16(const bf16* g, bf16* l) {
    __builtin_amdgcn_global_load_lds((const __attribute__((address_space(1))) void*)g,
                                     (__attribute__((address_space(3))) void*)l,
                                     16, 0, 0);
}

// ---------------- dequant: W[r][c] = lut[walks[r][c]] * sl[r] * sr[c] * 0.02 ----------------
__global__ __launch_bounds__(256) void dequant_kernel(const int* __restrict__ walks,
                                                      const float* __restrict__ lut,
                                                      const float* __restrict__ sl,
                                                      const float* __restrict__ sr,
                                                      bf16* __restrict__ W,
                                                      int colsLog2) {
    __shared__ float slut[256];
    slut[threadIdx.x] = lut[threadIdx.x] * WSCALE;
    __syncthreads();
    long base = ((long)blockIdx.x * 256 + threadIdx.x) * 8;
    int r = (int)(base >> colsLog2);
    int c = (int)(base & ((1 << colsLog2) - 1));
    float s = sl[r];
    const int4* wp = (const int4*)(walks + base);
    int4 w0 = wp[0];
    int4 w1 = wp[1];
    float4 s0 = *(const float4*)(sr + c);
    float4 s1 = *(const float4*)(sr + c + 4);
    alignas(16) bf16 o[8];
    o[0] = __float2bfloat16(slut[w0.x] * s0.x * s);
    o[1] = __float2bfloat16(slut[w0.y] * s0.y * s);
    o[2] = __float2bfloat16(slut[w0.z] * s0.z * s);
    o[3] = __float2bfloat16(slut[w0.w] * s0.w * s);
    o[4] = __float2bfloat16(slut[w1.x] * s1.x * s);
    o[5] = __float2bfloat16(slut[w1.y] * s1.y * s);
    o[6] = __float2bfloat16(slut[w1.z] * s1.z * s);
    o[7] = __float2bfloat16(slut[w1.w] * s1.w * s);
    *(uint4*)(W + base) = *(const uint4*)o;
}

// ---------------- x fp32 -> bf16 ----------------
__global__ __launch_bounds__(256) void cvt_bf16_kernel(const float* __restrict__ X,
                                                       bf16* __restrict__ Y) {
    long base = ((long)blockIdx.x * 256 + threadIdx.x) * 8;
    float4 a = *(const float4*)(X + base);
    float4 b = *(const float4*)(X + base + 4);
    alignas(16) bf16 o[8];
    o[0] = __float2bfloat16(a.x);
    o[1] = __float2bfloat16(a.y);
    o[2] = __float2bfloat16(a.z);
    o[3] = __float2bfloat16(a.w);
    o[4] = __float2bfloat16(b.x);
    o[5] = __float2bfloat16(b.y);
    o[6] = __float2bfloat16(b.z);
    o[7] = __float2bfloat16(b.w);
    *(uint4*)(Y + base) = *(const uint4*)o;
}

// LDS XOR swizzle (BK=32, 4 chunks of 8 bf16 per 64 B row):
//   chunk c of row r stored at slot s = (c + (r>>1)) & 3
// Writer (thread t stages 16 B at LDS byte offset t*16): row = t>>2, slot = t&3
//   -> global chunk c = ((t&3) - ((t>>3)&3)) & 3
// Reader (lane wants chunk cr = lane>>4 of row waveX + i*16 + m16):
//   slot = (cr + ((m16>>1)&3)) & 3   (waveX, i*16 contribute 0 mod 4 after >>1)
// Hand-verified: every 8-lane ds_read_b128 phase hits 8 distinct 4-bank groups.

// ---------------- fused gate+up GEMM ----------------
// G[M=4096, N=8192] = bf16( silu(xb @ Wg^T) * (xb @ Wu^T) )
// 128x128 tile, 256 threads = 4 waves (2x2 of 64x64), BK=32, dual accumulators.
__global__ __launch_bounds__(256, 2) void gemm_gateup(const bf16* __restrict__ A,
                                                      const bf16* __restrict__ Bg_,
                                                      const bf16* __restrict__ Bu_,
                                                      bf16* __restrict__ G) {
    __shared__ alignas(16) char smem[24576];   // 3 x 8 KB staging; epilogue reuses as T
    bf16* As  = (bf16*)smem;
    bf16* Bgs = (bf16*)(smem + 8192);
    bf16* Bus = (bf16*)(smem + 16384);

    const int t = threadIdx.x;
    const int mBase = blockIdx.y * 128;
    const int nBase = blockIdx.x * 128;
    const int K = D_MODEL;

    const int rowA = t >> 2;
    const int colO = (((t & 3) - ((t >> 3) & 3)) & 3) * 8;   // swizzled global chunk
    const bf16* Ag  = A   + (long)(mBase + rowA) * K + colO;
    const bf16* Bgg = Bg_ + (long)(nBase + rowA) * K + colO;
    const bf16* Bug = Bu_ + (long)(nBase + rowA) * K + colO;
    const long rstep = (long)64 * K;

    f32x4 accg[4][4], accu[4][4];
#pragma unroll
    for (int i = 0; i < 4; i++)
#pragma unroll
        for (int j = 0; j < 4; j++) {
            f32x4 z = {0.f, 0.f, 0.f, 0.f};
            accg[i][j] = z; accu[i][j] = z;
        }

    const int lane  = t & 63;
    const int wave  = t >> 6;
    const int waveM = (wave & 1) * 64;
    const int waveN = (wave >> 1) * 64;
    const int m16   = lane & 15;
    const int slot  = (((lane >> 4) + (m16 >> 1)) & 3) * 8;  // swizzled LDS chunk
    const bf16* Asr = As  + (waveM + m16) * 32 + slot;
    const bf16* Bgr = Bgs + (waveN + m16) * 32 + slot;
    const bf16* Bur = Bus + (waveN + m16) * 32 + slot;

    for (int k0 = 0; k0 < K; k0 += 32) {
        gld_lds16(Ag  + k0,         As  + t * 8);
        gld_lds16(Ag  + k0 + rstep, As  + 2048 + t * 8);
        gld_lds16(Bgg + k0,         Bgs + t * 8);
        gld_lds16(Bgg + k0 + rstep, Bgs + 2048 + t * 8);
        gld_lds16(Bug + k0,         Bus + t * 8);
        gld_lds16(Bug + k0 + rstep, Bus + 2048 + t * 8);
        __syncthreads();

        bf16x8 af[4], bg[4], bu[4];
#pragma unroll
        for (int i = 0; i < 4; i++) af[i] = *(const bf16x8*)(Asr + i * 512);
#pragma unroll
        for (int j = 0; j < 4; j++) bg[j] = *(const bf16x8*)(Bgr + j * 512);
#pragma unroll
        for (int j = 0; j < 4; j++) bu[j] = *(const bf16x8*)(Bur + j * 512);
#pragma unroll
        for (int i = 0; i < 4; i++)
#pragma unroll
            for (int j = 0; j < 4; j++) {
                accg[i][j] = __builtin_amdgcn_mfma_f32_16x16x32_bf16(af[i], bg[j], accg[i][j], 0, 0, 0);
                accu[i][j] = __builtin_amdgcn_mfma_f32_16x16x32_bf16(af[i], bu[j], accu[i][j], 0, 0, 0);
            }
        __syncthreads();
    }

    // epilogue: silu(g)*u -> per-wave LDS transpose T[16][68] fp32 -> coalesced bf16 stores
    float* Tw = (float*)smem + wave * 1088;   // 16*68 = 1088 dwords = 4352 B (16B aligned)
    const int rq = (lane >> 4) * 4;
#pragma unroll 1
    for (int i = 0; i < 4; i++) {
#pragma unroll
        for (int j = 0; j < 4; j++)
#pragma unroll
            for (int r = 0; r < 4; r++) {
                float g = accg[i][j][r];
                float u = accu[i][j][r];
                float h = (g / (1.0f + __expf(-g))) * u;
                Tw[(rq + r) * 68 + j * 16 + m16] = h;   // 0-conflict: 32 distinct banks/phase
            }
        __syncthreads();
#pragma unroll
        for (int s = 0; s < 4; s++) {
            int row = (lane >> 4) + 4 * s;
            f32x4 v = *(const f32x4*)(Tw + row * 68 + (m16 << 2));  // b128, 0-conflict
            union { ushort u16[4]; uint2 d; } o;
            o.u16[0] = __bfloat16_as_ushort(__float2bfloat16(v[0]));
            o.u16[1] = __bfloat16_as_ushort(__float2bfloat16(v[1]));
            o.u16[2] = __bfloat16_as_ushort(__float2bfloat16(v[2]));
            o.u16[3] = __bfloat16_as_ushort(__float2bfloat16(v[3]));
            long grow = mBase + waveM + i * 16 + row;
            int  gcol = nBase + waveN + (m16 << 2);
            *(uint2*)(G + grow * D_FF + gcol) = o.d;   // 16 lanes x 8 B = 128 B segments
        }
        __syncthreads();
    }
}

// ---------------- down GEMM: Out[4096, 2048] = G @ Wd^T, fp32 out ----------------
__global__ __launch_bounds__(256) void gemm_down(const bf16* __restrict__ A,
                                                 const bf16* __restrict__ B,
                                                 float* __restrict__ Out) {
    __shared__ alignas(16) char smem[17408];   // 2 x 8 KB staging; epilogue T = 17 KB
    bf16* As = (bf16*)smem;
    bf16* Bs = (bf16*)(smem + 8192);

    const int t = threadIdx.x;
    const int mBase = blockIdx.y * 128;
    const int nBase = blockIdx.x * 128;
    const int K = D_FF;

    const int rowA = t >> 2;
    const int colO = (((t & 3) - ((t >> 3) & 3)) & 3) * 8;
    const bf16* Ag = A + (long)(mBase + rowA) * K + colO;
    const bf16* Bg = B + (long)(nBase + rowA) * K + colO;
    const long rstep = (long)64 * K;

    f32x4 acc[4][4];
#pragma unroll
    for (int i = 0; i < 4; i++)
#pragma unroll
        for (int j = 0; j < 4; j++) {
            f32x4 z = {0.f, 0.f, 0.f, 0.f};
            acc[i][j] = z;
        }

    const int lane  = t & 63;
    const int wave  = t >> 6;
    const int waveM = (wave & 1) * 64;
    const int waveN = (wave >> 1) * 64;
    const int m16   = lane & 15;
    const int slot  = (((lane >> 4) + (m16 >> 1)) & 3) * 8;
    const bf16* Asr = As + (waveM + m16) * 32 + slot;
    const bf16* Bsr = Bs + (waveN + m16) * 32 + slot;

    for (int k0 = 0; k0 < K; k0 += 32) {
        gld_lds16(Ag + k0,         As + t * 8);
        gld_lds16(Ag + k0 + rstep, As + 2048 + t * 8);
        gld_lds16(Bg + k0,         Bs + t * 8);
        gld_lds16(Bg + k0 + rstep, Bs + 2048 + t * 8);
        __syncthreads();

        bf16x8 af[4], bfr[4];
#pragma unroll
        for (int i = 0; i < 4; i++) af[i]  = *(const bf16x8*)(Asr + i * 512);
#pragma unroll
        for (int j = 0; j < 4; j++) bfr[j] = *(const bf16x8*)(Bsr + j * 512);
#pragma unroll
        for (int i = 0; i < 4; i++)
#pragma unroll
            for (int j = 0; j < 4; j++)
                acc[i][j] = __builtin_amdgcn_mfma_f32_16x16x32_bf16(af[i], bfr[j], acc[i][j], 0, 0, 0);
        __syncthreads();
    }

    // epilogue: per-wave LDS transpose -> coalesced f32x4 stores (256 B segments)
    float* Tw = (float*)smem + wave * 1088;
    const int rq = (lane >> 4) * 4;
#pragma unroll 1
    for (int i = 0; i < 4; i++) {
#pragma unroll
        for (int j = 0; j < 4; j++)
#pragma unroll
            for (int r = 0; r < 4; r++)
                Tw[(rq + r) * 68 + j * 16 + m16] = acc[i][j][r];
        __syncthreads();
#pragma unroll
        for (int s = 0; s < 4; s++) {
            int row = (lane >> 4) + 4 * s;
            f32x4 v = *(const f32x4*)(Tw + row * 68 + (m16 << 2));
            long grow = mBase + waveM + i * 16 + row;
            int  gcol = nBase + waveN + (m16 << 2);
            *(f32x4*)(Out + grow * D_MODEL + gcol) = v;
        }
        __syncthreads();
    }
}

extern "C" void kernel_launch(void* const* d_in, const int* in_sizes, int n_in,
                              void* d_out, int out_size, void* d_ws, size_t ws_size,
                              hipStream_t stream) {
    (void)in_sizes; (void)n_in; (void)out_size; (void)ws_size;
    const float* x     = (const float*)d_in[0];
    const float* lut_g = (const float*)d_in[1];
    const float* lut_u = (const float*)d_in[2];
    const float* lut_d = (const float*)d_in[3];
    const int*   wk_g  = (const int*)d_in[4];
    const int*   wk_u  = (const int*)d_in[5];
    const int*   wk_d  = (const int*)d_in[6];
    const float* sl_g  = (const float*)d_in[7];
    const float* sr_g  = (const float*)d_in[8];
    const float* sl_u  = (const float*)d_in[9];
    const float* sr_u  = (const float*)d_in[10];
    const float* sl_d  = (const float*)d_in[11];
    const float* sr_d  = (const float*)d_in[12];

    char* ws = (char*)d_ws;
    bf16* xb = (bf16*)(ws);                                   // 16 MB
    bf16* Wg = (bf16*)(ws + (size_t)16 * 1024 * 1024);        // 32 MB
    bf16* Wu = (bf16*)(ws + (size_t)48 * 1024 * 1024);        // 32 MB
    bf16* G  = (bf16*)(ws + (size_t)80 * 1024 * 1024);        // 64 MB -> ws peak 144 MB
    bf16* Wd = Wg;                                            // reuse Wg slot after fused GEMM
    float* out = (float*)d_out;

    cvt_bf16_kernel<<<dim3(NTOK * D_MODEL / 2048), 256, 0, stream>>>(x, xb);
    dequant_kernel<<<dim3(D_FF * D_MODEL / 2048), 256, 0, stream>>>(wk_g, lut_g, sl_g, sr_g, Wg, 11);
    dequant_kernel<<<dim3(D_FF * D_MODEL / 2048), 256, 0, stream>>>(wk_u, lut_u, sl_u, sr_u, Wu, 11);

    // fused gate+up: G = bf16(silu(xb@Wg^T) * (xb@Wu^T))
    gemm_gateup<<<dim3(D_FF / 128, NTOK / 128), 256, 0, stream>>>(xb, Wg, Wu, G);

    dequant_kernel<<<dim3(D_MODEL * D_FF / 2048), 256, 0, stream>>>(wk_d, lut_d, sl_d, sr_d, Wd, 13);
    // down: out = G @ Wd^T (fp32)
    gemm_down<<<dim3(D_MODEL / 128, NTOK / 128), 256, 0, stream>>>(G, Wd, out);
}

// Round 3
// 692.029 us; speedup vs baseline: 6.4836x; 6.4836x over previous
//
#include <hip/hip_runtime.h>
#include <hip/hip_bf16.h>
#include <stdint.h>

#define D_MODEL 2048
#define D_FF    8192
#define NTOK    4096
#define WSCALE  0.02f

using bf16 = __hip_bfloat16;
typedef __bf16 bf16x8 __attribute__((ext_vector_type(8)));
typedef float  f32x4  __attribute__((ext_vector_type(4)));

// async global -> LDS, 16 B per lane (wave-uniform base + lane*16 layout)
__device__ __forceinline__ void gld_lds16(const bf16* g, bf16* l) {
    __builtin_amdgcn_global_load_lds((const __attribute__((address_space(1))) void*)g,
                                     (__attribute__((address_space(3))) void*)l,
                                     16, 0, 0);
}

// ---------------- dequant: W[r][c] = lut[walks[r][c]] * sl[r] * sr[c] * 0.02 ----------------
__global__ __launch_bounds__(256) void dequant_kernel(const int* __restrict__ walks,
                                                      const float* __restrict__ lut,
                                                      const float* __restrict__ sl,
                                                      const float* __restrict__ sr,
                                                      bf16* __restrict__ W,
                                                      int colsLog2) {
    __shared__ float slut[256];
    slut[threadIdx.x] = lut[threadIdx.x] * WSCALE;
    __syncthreads();
    long base = ((long)blockIdx.x * 256 + threadIdx.x) * 8;
    int r = (int)(base >> colsLog2);
    int c = (int)(base & ((1 << colsLog2) - 1));
    float s = sl[r];
    const int4* wp = (const int4*)(walks + base);
    int4 w0 = wp[0];
    int4 w1 = wp[1];
    float4 s0 = *(const float4*)(sr + c);
    float4 s1 = *(const float4*)(sr + c + 4);
    alignas(16) bf16 o[8];
    o[0] = __float2bfloat16(slut[w0.x] * s0.x * s);
    o[1] = __float2bfloat16(slut[w0.y] * s0.y * s);
    o[2] = __float2bfloat16(slut[w0.z] * s0.z * s);
    o[3] = __float2bfloat16(slut[w0.w] * s0.w * s);
    o[4] = __float2bfloat16(slut[w1.x] * s1.x * s);
    o[5] = __float2bfloat16(slut[w1.y] * s1.y * s);
    o[6] = __float2bfloat16(slut[w1.z] * s1.z * s);
    o[7] = __float2bfloat16(slut[w1.w] * s1.w * s);
    *(uint4*)(W + base) = *(const uint4*)o;
}

// ---------------- x fp32 -> bf16 ----------------
__global__ __launch_bounds__(256) void cvt_bf16_kernel(const float* __restrict__ X,
                                                       bf16* __restrict__ Y) {
    long base = ((long)blockIdx.x * 256 + threadIdx.x) * 8;
    float4 a = *(const float4*)(X + base);
    float4 b = *(const float4*)(X + base + 4);
    alignas(16) bf16 o[8];
    o[0] = __float2bfloat16(a.x);
    o[1] = __float2bfloat16(a.y);
    o[2] = __float2bfloat16(a.z);
    o[3] = __float2bfloat16(a.w);
    o[4] = __float2bfloat16(b.x);
    o[5] = __float2bfloat16(b.y);
    o[6] = __float2bfloat16(b.z);
    o[7] = __float2bfloat16(b.w);
    *(uint4*)(Y + base) = *(const uint4*)o;
}

// LDS XOR swizzle (BK=32, 4 chunks of 8 bf16 per 64 B row):
//   chunk c of row r stored at slot s = (c + (r>>1)) & 3
// Writer (thread t stages 16 B at LDS byte offset t*16): row = t>>2, slot = t&3
//   -> global chunk c = ((t&3) - ((t>>3)&3)) & 3
// Reader: slot = ((lane>>4) + ((m16>>1)&3)) & 3
// Verified R2: SQ_LDS_BANK_CONFLICT 1.68e7 -> 5.2e5.

// ---------------- fused gate+up GEMM ----------------
// G[M=4096, N=8192] = bf16( silu(xb @ Wg^T) * (xb @ Wu^T) )
// 128x128 tile, 256 threads = 4 waves (2x2 of 64x64), BK=32, dual accumulators.
// NOTE: epilogue loops MUST be fully unrolled — runtime indexing of acc arrays
// demotes them to scratch (R2: 17 GB spill traffic, 3.5x regression).
__global__ __launch_bounds__(256, 2) void gemm_gateup(const bf16* __restrict__ A,
                                                      const bf16* __restrict__ Bg_,
                                                      const bf16* __restrict__ Bu_,
                                                      bf16* __restrict__ G) {
    __shared__ alignas(16) char smem[24576];   // 3 x 8 KB staging; epilogue reuses as T
    bf16* As  = (bf16*)smem;
    bf16* Bgs = (bf16*)(smem + 8192);
    bf16* Bus = (bf16*)(smem + 16384);

    const int t = threadIdx.x;
    const int mBase = blockIdx.y * 128;
    const int nBase = blockIdx.x * 128;
    const int K = D_MODEL;

    const int rowA = t >> 2;
    const int colO = (((t & 3) - ((t >> 3) & 3)) & 3) * 8;   // swizzled global chunk
    const bf16* Ag  = A   + (long)(mBase + rowA) * K + colO;
    const bf16* Bgg = Bg_ + (long)(nBase + rowA) * K + colO;
    const bf16* Bug = Bu_ + (long)(nBase + rowA) * K + colO;
    const long rstep = (long)64 * K;

    f32x4 accg[4][4], accu[4][4];
#pragma unroll
    for (int i = 0; i < 4; i++)
#pragma unroll
        for (int j = 0; j < 4; j++) {
            f32x4 z = {0.f, 0.f, 0.f, 0.f};
            accg[i][j] = z; accu[i][j] = z;
        }

    const int lane  = t & 63;
    const int wave  = t >> 6;
    const int waveM = (wave & 1) * 64;
    const int waveN = (wave >> 1) * 64;
    const int m16   = lane & 15;
    const int slot  = (((lane >> 4) + (m16 >> 1)) & 3) * 8;  // swizzled LDS chunk
    const bf16* Asr = As  + (waveM + m16) * 32 + slot;
    const bf16* Bgr = Bgs + (waveN + m16) * 32 + slot;
    const bf16* Bur = Bus + (waveN + m16) * 32 + slot;

    for (int k0 = 0; k0 < K; k0 += 32) {
        gld_lds16(Ag  + k0,         As  + t * 8);
        gld_lds16(Ag  + k0 + rstep, As  + 2048 + t * 8);
        gld_lds16(Bgg + k0,         Bgs + t * 8);
        gld_lds16(Bgg + k0 + rstep, Bgs + 2048 + t * 8);
        gld_lds16(Bug + k0,         Bus + t * 8);
        gld_lds16(Bug + k0 + rstep, Bus + 2048 + t * 8);
        __syncthreads();

        bf16x8 af[4], bg[4], bu[4];
#pragma unroll
        for (int i = 0; i < 4; i++) af[i] = *(const bf16x8*)(Asr + i * 512);
#pragma unroll
        for (int j = 0; j < 4; j++) bg[j] = *(const bf16x8*)(Bgr + j * 512);
#pragma unroll
        for (int j = 0; j < 4; j++) bu[j] = *(const bf16x8*)(Bur + j * 512);
#pragma unroll
        for (int i = 0; i < 4; i++)
#pragma unroll
            for (int j = 0; j < 4; j++) {
                accg[i][j] = __builtin_amdgcn_mfma_f32_16x16x32_bf16(af[i], bg[j], accg[i][j], 0, 0, 0);
                accu[i][j] = __builtin_amdgcn_mfma_f32_16x16x32_bf16(af[i], bu[j], accu[i][j], 0, 0, 0);
            }
        __syncthreads();
    }

    // epilogue: silu(g)*u -> per-wave LDS transpose T[16][68] fp32 -> coalesced bf16 stores
    float* Tw = (float*)smem + wave * 1088;   // 16*68 = 1088 dwords = 4352 B (16B aligned)
    const int rq = (lane >> 4) * 4;
#pragma unroll
    for (int i = 0; i < 4; i++) {   // FULLY unrolled: i must be compile-time (see NOTE)
#pragma unroll
        for (int j = 0; j < 4; j++)
#pragma unroll
            for (int r = 0; r < 4; r++) {
                float g = accg[i][j][r];
                float u = accu[i][j][r];
                float h = (g / (1.0f + __expf(-g))) * u;
                Tw[(rq + r) * 68 + j * 16 + m16] = h;   // 0-conflict: 32 distinct banks/phase
            }
        __syncthreads();
#pragma unroll
        for (int s = 0; s < 4; s++) {
            int row = (lane >> 4) + 4 * s;
            f32x4 v = *(const f32x4*)(Tw + row * 68 + (m16 << 2));  // b128, 0-conflict
            union { ushort u16[4]; uint2 d; } o;
            o.u16[0] = __bfloat16_as_ushort(__float2bfloat16(v[0]));
            o.u16[1] = __bfloat16_as_ushort(__float2bfloat16(v[1]));
            o.u16[2] = __bfloat16_as_ushort(__float2bfloat16(v[2]));
            o.u16[3] = __bfloat16_as_ushort(__float2bfloat16(v[3]));
            long grow = mBase + waveM + i * 16 + row;
            int  gcol = nBase + waveN + (m16 << 2);
            *(uint2*)(G + grow * D_FF + gcol) = o.d;   // 16 lanes x 8 B = 128 B segments
        }
        __syncthreads();
    }
}

// ---------------- down GEMM: Out[4096, 2048] = G @ Wd^T, fp32 out ----------------
__global__ __launch_bounds__(256) void gemm_down(const bf16* __restrict__ A,
                                                 const bf16* __restrict__ B,
                                                 float* __restrict__ Out) {
    __shared__ alignas(16) char smem[17408];   // 2 x 8 KB staging; epilogue T = 17 KB
    bf16* As = (bf16*)smem;
    bf16* Bs = (bf16*)(smem + 8192);

    const int t = threadIdx.x;
    const int mBase = blockIdx.y * 128;
    const int nBase = blockIdx.x * 128;
    const int K = D_FF;

    const int rowA = t >> 2;
    const int colO = (((t & 3) - ((t >> 3) & 3)) & 3) * 8;
    const bf16* Ag = A + (long)(mBase + rowA) * K + colO;
    const bf16* Bg = B + (long)(nBase + rowA) * K + colO;
    const long rstep = (long)64 * K;

    f32x4 acc[4][4];
#pragma unroll
    for (int i = 0; i < 4; i++)
#pragma unroll
        for (int j = 0; j < 4; j++) {
            f32x4 z = {0.f, 0.f, 0.f, 0.f};
            acc[i][j] = z;
        }

    const int lane  = t & 63;
    const int wave  = t >> 6;
    const int waveM = (wave & 1) * 64;
    const int waveN = (wave >> 1) * 64;
    const int m16   = lane & 15;
    const int slot  = (((lane >> 4) + (m16 >> 1)) & 3) * 8;
    const bf16* Asr = As + (waveM + m16) * 32 + slot;
    const bf16* Bsr = Bs + (waveN + m16) * 32 + slot;

    for (int k0 = 0; k0 < K; k0 += 32) {
        gld_lds16(Ag + k0,         As + t * 8);
        gld_lds16(Ag + k0 + rstep, As + 2048 + t * 8);
        gld_lds16(Bg + k0,         Bs + t * 8);
        gld_lds16(Bg + k0 + rstep, Bs + 2048 + t * 8);
        __syncthreads();

        bf16x8 af[4], bfr[4];
#pragma unroll
        for (int i = 0; i < 4; i++) af[i]  = *(const bf16x8*)(Asr + i * 512);
#pragma unroll
        for (int j = 0; j < 4; j++) bfr[j] = *(const bf16x8*)(Bsr + j * 512);
#pragma unroll
        for (int i = 0; i < 4; i++)
#pragma unroll
            for (int j = 0; j < 4; j++)
                acc[i][j] = __builtin_amdgcn_mfma_f32_16x16x32_bf16(af[i], bfr[j], acc[i][j], 0, 0, 0);
        __syncthreads();
    }

    // epilogue: per-wave LDS transpose -> coalesced f32x4 stores (256 B segments)
    float* Tw = (float*)smem + wave * 1088;
    const int rq = (lane >> 4) * 4;
#pragma unroll
    for (int i = 0; i < 4; i++) {   // FULLY unrolled: i must be compile-time (see NOTE above)
#pragma unroll
        for (int j = 0; j < 4; j++)
#pragma unroll
            for (int r = 0; r < 4; r++)
                Tw[(rq + r) * 68 + j * 16 + m16] = acc[i][j][r];
        __syncthreads();
#pragma unroll
        for (int s = 0; s < 4; s++) {
            int row = (lane >> 4) + 4 * s;
            f32x4 v = *(const f32x4*)(Tw + row * 68 + (m16 << 2));
            long grow = mBase + waveM + i * 16 + row;
            int  gcol = nBase + waveN + (m16 << 2);
            *(f32x4*)(Out + grow * D_MODEL + gcol) = v;
        }
        __syncthreads();
    }
}

extern "C" void kernel_launch(void* const* d_in, const int* in_sizes, int n_in,
                              void* d_out, int out_size, void* d_ws, size_t ws_size,
                              hipStream_t stream) {
    (void)in_sizes; (void)n_in; (void)out_size; (void)ws_size;
    const float* x     = (const float*)d_in[0];
    const float* lut_g = (const float*)d_in[1];
    const float* lut_u = (const float*)d_in[2];
    const float* lut_d = (const float*)d_in[3];
    const int*   wk_g  = (const int*)d_in[4];
    const int*   wk_u  = (const int*)d_in[5];
    const int*   wk_d  = (const int*)d_in[6];
    const float* sl_g  = (const float*)d_in[7];
    const float* sr_g  = (const float*)d_in[8];
    const float* sl_u  = (const float*)d_in[9];
    const float* sr_u  = (const float*)d_in[10];
    const float* sl_d  = (const float*)d_in[11];
    const float* sr_d  = (const float*)d_in[12];

    char* ws = (char*)d_ws;
    bf16* xb = (bf16*)(ws);                                   // 16 MB
    bf16* Wg = (bf16*)(ws + (size_t)16 * 1024 * 1024);        // 32 MB
    bf16* Wu = (bf16*)(ws + (size_t)48 * 1024 * 1024);        // 32 MB
    bf16* G  = (bf16*)(ws + (size_t)80 * 1024 * 1024);        // 64 MB -> ws peak 144 MB
    bf16* Wd = Wg;                                            // reuse Wg slot after fused GEMM
    float* out = (float*)d_out;

    cvt_bf16_kernel<<<dim3(NTOK * D_MODEL / 2048), 256, 0, stream>>>(x, xb);
    dequant_kernel<<<dim3(D_FF * D_MODEL / 2048), 256, 0, stream>>>(wk_g, lut_g, sl_g, sr_g, Wg, 11);
    dequant_kernel<<<dim3(D_FF * D_MODEL / 2048), 256, 0, stream>>>(wk_u, lut_u, sl_u, sr_u, Wu, 11);

    // fused gate+up: G = bf16(silu(xb@Wg^T) * (xb@Wu^T))
    gemm_gateup<<<dim3(D_FF / 128, NTOK / 128), 256, 0, stream>>>(xb, Wg, Wu, G);

    dequant_kernel<<<dim3(D_MODEL * D_FF / 2048), 256, 0, stream>>>(wk_d, lut_d, sl_d, sr_d, Wd, 13);
    // down: out = G @ Wd^T (fp32)
    gemm_down<<<dim3(D_MODEL / 128, NTOK / 128), 256, 0, stream>>>(G, Wd, out);
}

// Round 4
// 641.261 us; speedup vs baseline: 6.9969x; 1.0792x over previous
//
#include <hip/hip_runtime.h>
#include <hip/hip_bf16.h>
#include <stdint.h>

#define D_MODEL 2048
#define D_FF    8192
#define NTOK    4096
#define WSCALE  0.02f

using bf16 = __hip_bfloat16;
typedef __bf16 bf16x8 __attribute__((ext_vector_type(8)));
typedef float  f32x4  __attribute__((ext_vector_type(4)));

// async global -> LDS, 16 B per lane (wave-uniform base + lane*16 layout)
__device__ __forceinline__ void gld_lds16(const bf16* g, bf16* l) {
    __builtin_amdgcn_global_load_lds((const __attribute__((address_space(1))) void*)g,
                                     (__attribute__((address_space(3))) void*)l,
                                     16, 0, 0);
}

// ---------------- standalone dequant (fallback when ws can't hold separate Wd) --------------
__global__ __launch_bounds__(256) void dequant_kernel(const int* __restrict__ walks,
                                                      const float* __restrict__ lut,
                                                      const float* __restrict__ sl,
                                                      const float* __restrict__ sr,
                                                      bf16* __restrict__ W,
                                                      int colsLog2) {
    __shared__ float slut[256];
    slut[threadIdx.x] = lut[threadIdx.x] * WSCALE;
    __syncthreads();
    long base = ((long)blockIdx.x * 256 + threadIdx.x) * 8;
    int r = (int)(base >> colsLog2);
    int c = (int)(base & ((1 << colsLog2) - 1));
    float s = sl[r];
    const int4* wp = (const int4*)(walks + base);
    int4 w0 = wp[0];
    int4 w1 = wp[1];
    float4 s0 = *(const float4*)(sr + c);
    float4 s1 = *(const float4*)(sr + c + 4);
    alignas(16) bf16 o[8];
    o[0] = __float2bfloat16(slut[w0.x] * s0.x * s);
    o[1] = __float2bfloat16(slut[w0.y] * s0.y * s);
    o[2] = __float2bfloat16(slut[w0.z] * s0.z * s);
    o[3] = __float2bfloat16(slut[w0.w] * s0.w * s);
    o[4] = __float2bfloat16(slut[w1.x] * s1.x * s);
    o[5] = __float2bfloat16(slut[w1.y] * s1.y * s);
    o[6] = __float2bfloat16(slut[w1.z] * s1.z * s);
    o[7] = __float2bfloat16(slut[w1.w] * s1.w * s);
    *(uint4*)(W + base) = *(const uint4*)o;
}

// ---------------- merged prep: x->bf16 + up to 3 dequants, one launch ----------------
// blocks [0,4096): cvt; [4096,12288): gate; [12288,20480): up; [20480,28672): down (if Wd)
__global__ __launch_bounds__(256) void prep_kernel(const float* __restrict__ x, bf16* __restrict__ xb,
    const int* __restrict__ wk_g, const float* __restrict__ lut_g,
    const float* __restrict__ sl_g, const float* __restrict__ sr_g, bf16* __restrict__ Wg,
    const int* __restrict__ wk_u, const float* __restrict__ lut_u,
    const float* __restrict__ sl_u, const float* __restrict__ sr_u, bf16* __restrict__ Wu,
    const int* __restrict__ wk_d, const float* __restrict__ lut_d,
    const float* __restrict__ sl_d, const float* __restrict__ sr_d, bf16* __restrict__ Wd) {
    const int t = threadIdx.x;
    const int b = blockIdx.x;
    if (b < 4096) {
        long base = ((long)b * 256 + t) * 8;
        float4 a = *(const float4*)(x + base);
        float4 v = *(const float4*)(x + base + 4);
        alignas(16) bf16 o[8];
        o[0] = __float2bfloat16(a.x); o[1] = __float2bfloat16(a.y);
        o[2] = __float2bfloat16(a.z); o[3] = __float2bfloat16(a.w);
        o[4] = __float2bfloat16(v.x); o[5] = __float2bfloat16(v.y);
        o[6] = __float2bfloat16(v.z); o[7] = __float2bfloat16(v.w);
        *(uint4*)(xb + base) = *(const uint4*)o;
        return;
    }
    const int* wk; const float* lut; const float* sl; const float* sr; bf16* W;
    int clog, bb;
    if (b < 12288)      { wk = wk_g; lut = lut_g; sl = sl_g; sr = sr_g; W = Wg; clog = 11; bb = b - 4096; }
    else if (b < 20480) { wk = wk_u; lut = lut_u; sl = sl_u; sr = sr_u; W = Wu; clog = 11; bb = b - 12288; }
    else                { wk = wk_d; lut = lut_d; sl = sl_d; sr = sr_d; W = Wd; clog = 13; bb = b - 20480; }
    __shared__ float slut[256];
    slut[t] = lut[t] * WSCALE;
    __syncthreads();
    long base = ((long)bb * 256 + t) * 8;
    int r = (int)(base >> clog);
    int c = (int)(base & ((1 << clog) - 1));
    float s = sl[r];
    const int4* wp = (const int4*)(wk + base);
    int4 w0 = wp[0];
    int4 w1 = wp[1];
    float4 s0 = *(const float4*)(sr + c);
    float4 s1 = *(const float4*)(sr + c + 4);
    alignas(16) bf16 o[8];
    o[0] = __float2bfloat16(slut[w0.x] * s0.x * s);
    o[1] = __float2bfloat16(slut[w0.y] * s0.y * s);
    o[2] = __float2bfloat16(slut[w0.z] * s0.z * s);
    o[3] = __float2bfloat16(slut[w0.w] * s0.w * s);
    o[4] = __float2bfloat16(slut[w1.x] * s1.x * s);
    o[5] = __float2bfloat16(slut[w1.y] * s1.y * s);
    o[6] = __float2bfloat16(slut[w1.z] * s1.z * s);
    o[7] = __float2bfloat16(slut[w1.w] * s1.w * s);
    *(uint4*)(W + base) = *(const uint4*)o;
}

// LDS XOR swizzle, BK=64 (8 chunks of 8 bf16 per 128 B row; row stride = 32 banks):
//   chunk c of row r stored at slot s = (c + r) & 7
// Writer pass p, thread t -> LDS offset p*4096B + t*16B: row = 32p + (t>>3), slot = t&7
//   -> global chunk c = ((t&7) - ((t>>3)&7)) & 7   (32p = 0 mod 8)
// Reader: logical chunk cl = (lane>>4) + 4*ks, row = waveX + i*16 + m16
//   -> slot = (cl + (m16&7)) & 7; ks=1 slot = ks0_slot ^ 4
// Hand-verified: every 8-lane ds_read_b128 phase hits 8 distinct 4-bank groups (both r/w).
// NOTE: epilogue acc loops MUST stay fully unrolled — runtime idx -> scratch spill (R2).

// ---------------- fused gate+up GEMM, BK=64 ----------------
// G[4096, 8192] = bf16( silu(xb @ Wg^T) * (xb @ Wu^T) ); 128x128 tile, 4 waves 2x2.
__global__ __launch_bounds__(256, 2) void gemm_gateup(const bf16* __restrict__ A,
                                                      const bf16* __restrict__ Bg_,
                                                      const bf16* __restrict__ Bu_,
                                                      bf16* __restrict__ G) {
    __shared__ alignas(16) char smem[49152];   // 3 x 16 KB staging; epilogue reuses as T
    bf16* As  = (bf16*)smem;
    bf16* Bgs = (bf16*)(smem + 16384);
    bf16* Bus = (bf16*)(smem + 32768);

    const int t = threadIdx.x;
    const int mBase = blockIdx.y * 128;
    const int nBase = blockIdx.x * 128;
    const int K = D_MODEL;

    const int srow = t >> 3;                                  // 0..31
    const int colO = (((t & 7) - ((t >> 3) & 7)) & 7) * 8;    // swizzled global chunk
    const bf16* Ag  = A   + (long)(mBase + srow) * K + colO;
    const bf16* Bgg = Bg_ + (long)(nBase + srow) * K + colO;
    const bf16* Bug = Bu_ + (long)(nBase + srow) * K + colO;
    const long rstep = (long)32 * K;

    f32x4 accg[4][4], accu[4][4];
#pragma unroll
    for (int i = 0; i < 4; i++)
#pragma unroll
        for (int j = 0; j < 4; j++) {
            f32x4 z = {0.f, 0.f, 0.f, 0.f};
            accg[i][j] = z; accu[i][j] = z;
        }

    const int lane  = t & 63;
    const int wave  = t >> 6;
    const int waveM = (wave & 1) * 64;
    const int waveN = (wave >> 1) * 64;
    const int m16   = lane & 15;
    const int s0    = (((lane >> 4) + (m16 & 7)) & 7) * 8;    // ks=0 slot (elems)
    const bf16* Asr0 = As  + (waveM + m16) * 64 + s0;
    const bf16* Bgr0 = Bgs + (waveN + m16) * 64 + s0;
    const bf16* Bur0 = Bus + (waveN + m16) * 64 + s0;
    const int sx = (s0 ^ 32) - s0;                            // ks=1 slot delta (slot^4)

    for (int k0 = 0; k0 < K; k0 += 64) {
#pragma unroll
        for (int p = 0; p < 4; p++) {
            gld_lds16(Ag  + k0 + p * rstep, As  + p * 2048 + t * 8);
            gld_lds16(Bgg + k0 + p * rstep, Bgs + p * 2048 + t * 8);
            gld_lds16(Bug + k0 + p * rstep, Bus + p * 2048 + t * 8);
        }
        __syncthreads();

#pragma unroll
        for (int ks = 0; ks < 2; ks++) {
            const int d = ks ? sx : 0;
            bf16x8 af[4], bg[4], bu[4];
#pragma unroll
            for (int i = 0; i < 4; i++) af[i] = *(const bf16x8*)(Asr0 + d + i * 1024);
#pragma unroll
            for (int j = 0; j < 4; j++) bg[j] = *(const bf16x8*)(Bgr0 + d + j * 1024);
#pragma unroll
            for (int j = 0; j < 4; j++) bu[j] = *(const bf16x8*)(Bur0 + d + j * 1024);
#pragma unroll
            for (int i = 0; i < 4; i++)
#pragma unroll
                for (int j = 0; j < 4; j++) {
                    accg[i][j] = __builtin_amdgcn_mfma_f32_16x16x32_bf16(af[i], bg[j], accg[i][j], 0, 0, 0);
                    accu[i][j] = __builtin_amdgcn_mfma_f32_16x16x32_bf16(af[i], bu[j], accu[i][j], 0, 0, 0);
                }
        }
        __syncthreads();
    }

    // epilogue: silu(g)*u -> per-wave LDS transpose T[16][68] fp32 -> coalesced bf16 stores
    float* Tw = (float*)smem + wave * 1088;
    const int rq = (lane >> 4) * 4;
#pragma unroll
    for (int i = 0; i < 4; i++) {
#pragma unroll
        for (int j = 0; j < 4; j++)
#pragma unroll
            for (int r = 0; r < 4; r++) {
                float g = accg[i][j][r];
                float u = accu[i][j][r];
                float h = (g / (1.0f + __expf(-g))) * u;
                Tw[(rq + r) * 68 + j * 16 + m16] = h;
            }
        __syncthreads();
#pragma unroll
        for (int s = 0; s < 4; s++) {
            int row = (lane >> 4) + 4 * s;
            f32x4 v = *(const f32x4*)(Tw + row * 68 + (m16 << 2));
            union { ushort u16[4]; uint2 d; } o;
            o.u16[0] = __bfloat16_as_ushort(__float2bfloat16(v[0]));
            o.u16[1] = __bfloat16_as_ushort(__float2bfloat16(v[1]));
            o.u16[2] = __bfloat16_as_ushort(__float2bfloat16(v[2]));
            o.u16[3] = __bfloat16_as_ushort(__float2bfloat16(v[3]));
            long grow = mBase + waveM + i * 16 + row;
            int  gcol = nBase + waveN + (m16 << 2);
            *(uint2*)(G + grow * D_FF + gcol) = o.d;
        }
        __syncthreads();
    }
}

// ---------------- down GEMM, BK=64: Out[4096, 2048] = G @ Wd^T, fp32 out ----------------
__global__ __launch_bounds__(256, 2) void gemm_down(const bf16* __restrict__ A,
                                                    const bf16* __restrict__ B,
                                                    float* __restrict__ Out) {
    __shared__ alignas(16) char smem[32768];   // 2 x 16 KB staging; epilogue T = 17408 B
    bf16* As = (bf16*)smem;
    bf16* Bs = (bf16*)(smem + 16384);

    const int t = threadIdx.x;
    const int mBase = blockIdx.y * 128;
    const int nBase = blockIdx.x * 128;
    const int K = D_FF;

    const int srow = t >> 3;
    const int colO = (((t & 7) - ((t >> 3) & 7)) & 7) * 8;
    const bf16* Ag = A + (long)(mBase + srow) * K + colO;
    const bf16* Bg = B + (long)(nBase + srow) * K + colO;
    const long rstep = (long)32 * K;

    f32x4 acc[4][4];
#pragma unroll
    for (int i = 0; i < 4; i++)
#pragma unroll
        for (int j = 0; j < 4; j++) {
            f32x4 z = {0.f, 0.f, 0.f, 0.f};
            acc[i][j] = z;
        }

    const int lane  = t & 63;
    const int wave  = t >> 6;
    const int waveM = (wave & 1) * 64;
    const int waveN = (wave >> 1) * 64;
    const int m16   = lane & 15;
    const int s0    = (((lane >> 4) + (m16 & 7)) & 7) * 8;
    const bf16* Asr0 = As + (waveM + m16) * 64 + s0;
    const bf16* Bsr0 = Bs + (waveN + m16) * 64 + s0;
    const int sx = (s0 ^ 32) - s0;

    for (int k0 = 0; k0 < K; k0 += 64) {
#pragma unroll
        for (int p = 0; p < 4; p++) {
            gld_lds16(Ag + k0 + p * rstep, As + p * 2048 + t * 8);
            gld_lds16(Bg + k0 + p * rstep, Bs + p * 2048 + t * 8);
        }
        __syncthreads();

#pragma unroll
        for (int ks = 0; ks < 2; ks++) {
            const int d = ks ? sx : 0;
            bf16x8 af[4], bfr[4];
#pragma unroll
            for (int i = 0; i < 4; i++) af[i]  = *(const bf16x8*)(Asr0 + d + i * 1024);
#pragma unroll
            for (int j = 0; j < 4; j++) bfr[j] = *(const bf16x8*)(Bsr0 + d + j * 1024);
#pragma unroll
            for (int i = 0; i < 4; i++)
#pragma unroll
                for (int j = 0; j < 4; j++)
                    acc[i][j] = __builtin_amdgcn_mfma_f32_16x16x32_bf16(af[i], bfr[j], acc[i][j], 0, 0, 0);
        }
        __syncthreads();
    }

    // epilogue: per-wave LDS transpose -> coalesced f32x4 stores (256 B segments)
    float* Tw = (float*)smem + wave * 1088;
    const int rq = (lane >> 4) * 4;
#pragma unroll
    for (int i = 0; i < 4; i++) {
#pragma unroll
        for (int j = 0; j < 4; j++)
#pragma unroll
            for (int r = 0; r < 4; r++)
                Tw[(rq + r) * 68 + j * 16 + m16] = acc[i][j][r];
        __syncthreads();
#pragma unroll
        for (int s = 0; s < 4; s++) {
            int row = (lane >> 4) + 4 * s;
            f32x4 v = *(const f32x4*)(Tw + row * 68 + (m16 << 2));
            long grow = mBase + waveM + i * 16 + row;
            int  gcol = nBase + waveN + (m16 << 2);
            *(f32x4*)(Out + grow * D_MODEL + gcol) = v;
        }
        __syncthreads();
    }
}

extern "C" void kernel_launch(void* const* d_in, const int* in_sizes, int n_in,
                              void* d_out, int out_size, void* d_ws, size_t ws_size,
                              hipStream_t stream) {
    (void)in_sizes; (void)n_in; (void)out_size;
    const float* x     = (const float*)d_in[0];
    const float* lut_g = (const float*)d_in[1];
    const float* lut_u = (const float*)d_in[2];
    const float* lut_d = (const float*)d_in[3];
    const int*   wk_g  = (const int*)d_in[4];
    const int*   wk_u  = (const int*)d_in[5];
    const int*   wk_d  = (const int*)d_in[6];
    const float* sl_g  = (const float*)d_in[7];
    const float* sr_g  = (const float*)d_in[8];
    const float* sl_u  = (const float*)d_in[9];
    const float* sr_u  = (const float*)d_in[10];
    const float* sl_d  = (const float*)d_in[11];
    const float* sr_d  = (const float*)d_in[12];

    char* ws = (char*)d_ws;
    bf16* xb = (bf16*)(ws);                                   // 16 MB
    bf16* Wg = (bf16*)(ws + (size_t)16 * 1024 * 1024);        // 32 MB
    bf16* Wu = (bf16*)(ws + (size_t)48 * 1024 * 1024);        // 32 MB
    bf16* G  = (bf16*)(ws + (size_t)80 * 1024 * 1024);        // 64 MB
    const bool sepWd = ws_size >= (size_t)176 * 1024 * 1024;  // room for separate Wd?
    bf16* Wd = sepWd ? (bf16*)(ws + (size_t)144 * 1024 * 1024) : Wg;
    float* out = (float*)d_out;

    // prep: cvt + gate/up dequant (+ down dequant if Wd has its own slot)
    prep_kernel<<<dim3(sepWd ? 28672 : 20480), 256, 0, stream>>>(
        x, xb, wk_g, lut_g, sl_g, sr_g, Wg, wk_u, lut_u, sl_u, sr_u, Wu,
        wk_d, lut_d, sl_d, sr_d, sepWd ? Wd : nullptr);

    // fused gate+up: G = bf16(silu(xb@Wg^T) * (xb@Wu^T))
    gemm_gateup<<<dim3(D_FF / 128, NTOK / 128), 256, 0, stream>>>(xb, Wg, Wu, G);

    if (!sepWd)  // Wd overwrites Wg; must wait for gateup
        dequant_kernel<<<dim3(D_MODEL * D_FF / 2048), 256, 0, stream>>>(wk_d, lut_d, sl_d, sr_d, Wd, 13);

    // down: out = G @ Wd^T (fp32)
    gemm_down<<<dim3(D_MODEL / 128, NTOK / 128), 256, 0, stream>>>(G, Wd, out);
}

// Round 5
// 640.639 us; speedup vs baseline: 7.0037x; 1.0010x over previous
//
#include <hip/hip_runtime.h>
#include <hip/hip_bf16.h>
#include <stdint.h>

#define D_MODEL 2048
#define D_FF    8192
#define NTOK    4096
#define WSCALE  0.02f

using bf16 = __hip_bfloat16;
typedef __bf16 bf16x8 __attribute__((ext_vector_type(8)));
typedef float  f32x4  __attribute__((ext_vector_type(4)));

// async global -> LDS, 16 B per lane (wave-uniform base + lane*16 layout)
__device__ __forceinline__ void gld_lds16(const bf16* g, bf16* l) {
    __builtin_amdgcn_global_load_lds((const __attribute__((address_space(1))) void*)g,
                                     (__attribute__((address_space(3))) void*)l,
                                     16, 0, 0);
}

// ---------------- standalone dequant (fallback when ws can't hold separate Wd) --------------
__global__ __launch_bounds__(256) void dequant_kernel(const int* __restrict__ walks,
                                                      const float* __restrict__ lut,
                                                      const float* __restrict__ sl,
                                                      const float* __restrict__ sr,
                                                      bf16* __restrict__ W,
                                                      int colsLog2) {
    __shared__ float slut[256];
    slut[threadIdx.x] = lut[threadIdx.x] * WSCALE;
    __syncthreads();
    long base = ((long)blockIdx.x * 256 + threadIdx.x) * 8;
    int r = (int)(base >> colsLog2);
    int c = (int)(base & ((1 << colsLog2) - 1));
    float s = sl[r];
    const int4* wp = (const int4*)(walks + base);
    int4 w0 = wp[0];
    int4 w1 = wp[1];
    float4 s0 = *(const float4*)(sr + c);
    float4 s1 = *(const float4*)(sr + c + 4);
    alignas(16) bf16 o[8];
    o[0] = __float2bfloat16(slut[w0.x] * s0.x * s);
    o[1] = __float2bfloat16(slut[w0.y] * s0.y * s);
    o[2] = __float2bfloat16(slut[w0.z] * s0.z * s);
    o[3] = __float2bfloat16(slut[w0.w] * s0.w * s);
    o[4] = __float2bfloat16(slut[w1.x] * s1.x * s);
    o[5] = __float2bfloat16(slut[w1.y] * s1.y * s);
    o[6] = __float2bfloat16(slut[w1.z] * s1.z * s);
    o[7] = __float2bfloat16(slut[w1.w] * s1.w * s);
    *(uint4*)(W + base) = *(const uint4*)o;
}

// ---------------- merged prep: x->bf16 + up to 3 dequants, one launch ----------------
__global__ __launch_bounds__(256) void prep_kernel(const float* __restrict__ x, bf16* __restrict__ xb,
    const int* __restrict__ wk_g, const float* __restrict__ lut_g,
    const float* __restrict__ sl_g, const float* __restrict__ sr_g, bf16* __restrict__ Wg,
    const int* __restrict__ wk_u, const float* __restrict__ lut_u,
    const float* __restrict__ sl_u, const float* __restrict__ sr_u, bf16* __restrict__ Wu,
    const int* __restrict__ wk_d, const float* __restrict__ lut_d,
    const float* __restrict__ sl_d, const float* __restrict__ sr_d, bf16* __restrict__ Wd) {
    const int t = threadIdx.x;
    const int b = blockIdx.x;
    if (b < 4096) {
        long base = ((long)b * 256 + t) * 8;
        float4 a = *(const float4*)(x + base);
        float4 v = *(const float4*)(x + base + 4);
        alignas(16) bf16 o[8];
        o[0] = __float2bfloat16(a.x); o[1] = __float2bfloat16(a.y);
        o[2] = __float2bfloat16(a.z); o[3] = __float2bfloat16(a.w);
        o[4] = __float2bfloat16(v.x); o[5] = __float2bfloat16(v.y);
        o[6] = __float2bfloat16(v.z); o[7] = __float2bfloat16(v.w);
        *(uint4*)(xb + base) = *(const uint4*)o;
        return;
    }
    const int* wk; const float* lut; const float* sl; const float* sr; bf16* W;
    int clog, bb;
    if (b < 12288)      { wk = wk_g; lut = lut_g; sl = sl_g; sr = sr_g; W = Wg; clog = 11; bb = b - 4096; }
    else if (b < 20480) { wk = wk_u; lut = lut_u; sl = sl_u; sr = sr_u; W = Wu; clog = 11; bb = b - 12288; }
    else                { wk = wk_d; lut = lut_d; sl = sl_d; sr = sr_d; W = Wd; clog = 13; bb = b - 20480; }
    __shared__ float slut[256];
    slut[t] = lut[t] * WSCALE;
    __syncthreads();
    long base = ((long)bb * 256 + t) * 8;
    int r = (int)(base >> clog);
    int c = (int)(base & ((1 << clog) - 1));
    float s = sl[r];
    const int4* wp = (const int4*)(wk + base);
    int4 w0 = wp[0];
    int4 w1 = wp[1];
    float4 s0 = *(const float4*)(sr + c);
    float4 s1 = *(const float4*)(sr + c + 4);
    alignas(16) bf16 o[8];
    o[0] = __float2bfloat16(slut[w0.x] * s0.x * s);
    o[1] = __float2bfloat16(slut[w0.y] * s0.y * s);
    o[2] = __float2bfloat16(slut[w0.z] * s0.z * s);
    o[3] = __float2bfloat16(slut[w0.w] * s0.w * s);
    o[4] = __float2bfloat16(slut[w1.x] * s1.x * s);
    o[5] = __float2bfloat16(slut[w1.y] * s1.y * s);
    o[6] = __float2bfloat16(slut[w1.z] * s1.z * s);
    o[7] = __float2bfloat16(slut[w1.w] * s1.w * s);
    *(uint4*)(W + base) = *(const uint4*)o;
}

// gateup LDS XOR swizzle, BK=64 (8 chunks of 8 bf16 per 128 B row):
//   chunk c of row r at slot (c + r) & 7. Verified R2/R4: conflicts 1.68e7 -> 5.2e5.
// NOTE: epilogue acc loops MUST stay fully unrolled — runtime idx -> scratch spill (R2).

// ---------------- fused gate+up GEMM, BK=64 (unchanged from R4: 291 us, 945 TF) -------------
__global__ __launch_bounds__(256, 2) void gemm_gateup(const bf16* __restrict__ A,
                                                      const bf16* __restrict__ Bg_,
                                                      const bf16* __restrict__ Bu_,
                                                      bf16* __restrict__ G) {
    __shared__ alignas(16) char smem[49152];
    bf16* As  = (bf16*)smem;
    bf16* Bgs = (bf16*)(smem + 16384);
    bf16* Bus = (bf16*)(smem + 32768);

    const int t = threadIdx.x;
    const int mBase = blockIdx.y * 128;
    const int nBase = blockIdx.x * 128;
    const int K = D_MODEL;

    const int srow = t >> 3;
    const int colO = (((t & 7) - ((t >> 3) & 7)) & 7) * 8;
    const bf16* Ag  = A   + (long)(mBase + srow) * K + colO;
    const bf16* Bgg = Bg_ + (long)(nBase + srow) * K + colO;
    const bf16* Bug = Bu_ + (long)(nBase + srow) * K + colO;
    const long rstep = (long)32 * K;

    f32x4 accg[4][4], accu[4][4];
#pragma unroll
    for (int i = 0; i < 4; i++)
#pragma unroll
        for (int j = 0; j < 4; j++) {
            f32x4 z = {0.f, 0.f, 0.f, 0.f};
            accg[i][j] = z; accu[i][j] = z;
        }

    const int lane  = t & 63;
    const int wave  = t >> 6;
    const int waveM = (wave & 1) * 64;
    const int waveN = (wave >> 1) * 64;
    const int m16   = lane & 15;
    const int s0    = (((lane >> 4) + (m16 & 7)) & 7) * 8;
    const bf16* Asr0 = As  + (waveM + m16) * 64 + s0;
    const bf16* Bgr0 = Bgs + (waveN + m16) * 64 + s0;
    const bf16* Bur0 = Bus + (waveN + m16) * 64 + s0;
    const int sx = (s0 ^ 32) - s0;

    for (int k0 = 0; k0 < K; k0 += 64) {
#pragma unroll
        for (int p = 0; p < 4; p++) {
            gld_lds16(Ag  + k0 + p * rstep, As  + p * 2048 + t * 8);
            gld_lds16(Bgg + k0 + p * rstep, Bgs + p * 2048 + t * 8);
            gld_lds16(Bug + k0 + p * rstep, Bus + p * 2048 + t * 8);
        }
        __syncthreads();

#pragma unroll
        for (int ks = 0; ks < 2; ks++) {
            const int d = ks ? sx : 0;
            bf16x8 af[4], bg[4], bu[4];
#pragma unroll
            for (int i = 0; i < 4; i++) af[i] = *(const bf16x8*)(Asr0 + d + i * 1024);
#pragma unroll
            for (int j = 0; j < 4; j++) bg[j] = *(const bf16x8*)(Bgr0 + d + j * 1024);
#pragma unroll
            for (int j = 0; j < 4; j++) bu[j] = *(const bf16x8*)(Bur0 + d + j * 1024);
#pragma unroll
            for (int i = 0; i < 4; i++)
#pragma unroll
                for (int j = 0; j < 4; j++) {
                    accg[i][j] = __builtin_amdgcn_mfma_f32_16x16x32_bf16(af[i], bg[j], accg[i][j], 0, 0, 0);
                    accu[i][j] = __builtin_amdgcn_mfma_f32_16x16x32_bf16(af[i], bu[j], accu[i][j], 0, 0, 0);
                }
        }
        __syncthreads();
    }

    float* Tw = (float*)smem + wave * 1088;
    const int rq = (lane >> 4) * 4;
#pragma unroll
    for (int i = 0; i < 4; i++) {
#pragma unroll
        for (int j = 0; j < 4; j++)
#pragma unroll
            for (int r = 0; r < 4; r++) {
                float g = accg[i][j][r];
                float u = accu[i][j][r];
                float h = (g / (1.0f + __expf(-g))) * u;
                Tw[(rq + r) * 68 + j * 16 + m16] = h;
            }
        __syncthreads();
#pragma unroll
        for (int s = 0; s < 4; s++) {
            int row = (lane >> 4) + 4 * s;
            f32x4 v = *(const f32x4*)(Tw + row * 68 + (m16 << 2));
            union { ushort u16[4]; uint2 d; } o;
            o.u16[0] = __bfloat16_as_ushort(__float2bfloat16(v[0]));
            o.u16[1] = __bfloat16_as_ushort(__float2bfloat16(v[1]));
            o.u16[2] = __bfloat16_as_ushort(__float2bfloat16(v[2]));
            o.u16[3] = __bfloat16_as_ushort(__float2bfloat16(v[3]));
            long grow = mBase + waveM + i * 16 + row;
            int  gcol = nBase + waveN + (m16 << 2);
            *(uint2*)(G + grow * D_FF + gcol) = o.d;
        }
        __syncthreads();
    }
}

// ---------------- down GEMM, BK=128: Out[4096, 2048] = G @ Wd^T, fp32 out ----------------
// 16-slot swizzle (BK=128: 16 chunks of 8 bf16 per 256 B row):
//   chunk c of row r at slot (c + r) & 15.
// Writer pass p (16 rows/pass), thread t -> row 16p + (t>>4), slot t&15
//   -> global chunk c = ((t&15) - ((t>>4)&15)) & 15.
// Reader: chunk cl = (lane>>4) + 4*ks, row = m16 (mod 16) -> slot = (cl + m16) & 15.
// Bank math: row stride 256 B = 0 mod 32 banks; slot*16B -> bank group (slot&7)*4;
// each 8-lane b128 phase has distinct (slot&7) -> 8 distinct 4-bank groups, 0-conflict.
__global__ __launch_bounds__(256, 2) void gemm_down(const bf16* __restrict__ A,
                                                    const bf16* __restrict__ B,
                                                    float* __restrict__ Out) {
    __shared__ alignas(16) char smem[65536];   // 2 x 32 KB staging; epilogue T = 17408 B
    bf16* As = (bf16*)smem;
    bf16* Bs = (bf16*)(smem + 32768);

    const int t = threadIdx.x;
    const int mBase = blockIdx.y * 128;
    const int nBase = blockIdx.x * 128;
    const int K = D_FF;

    const int srow = t >> 4;                                    // 0..15
    const int colO = (((t & 15) - ((t >> 4) & 15)) & 15) * 8;   // swizzled global chunk
    const bf16* Ag = A + (long)(mBase + srow) * K + colO;
    const bf16* Bg = B + (long)(nBase + srow) * K + colO;
    const long rstep = (long)16 * K;

    f32x4 acc[4][4];
#pragma unroll
    for (int i = 0; i < 4; i++)
#pragma unroll
        for (int j = 0; j < 4; j++) {
            f32x4 z = {0.f, 0.f, 0.f, 0.f};
            acc[i][j] = z;
        }

    const int lane  = t & 63;
    const int wave  = t >> 6;
    const int waveM = (wave & 1) * 64;
    const int waveN = (wave >> 1) * 64;
    const int m16   = lane & 15;
    const int c0    = lane >> 4;                                // 0..3
    const bf16* Asr = As + (waveM + m16) * 128;                 // row base; slot added per ks
    const bf16* Bsr = Bs + (waveN + m16) * 128;

    for (int k0 = 0; k0 < K; k0 += 128) {
#pragma unroll
        for (int p = 0; p < 8; p++) {
            gld_lds16(Ag + k0 + p * rstep, As + p * 2048 + t * 8);
            gld_lds16(Bg + k0 + p * rstep, Bs + p * 2048 + t * 8);
        }
        __syncthreads();

#pragma unroll
        for (int ks = 0; ks < 4; ks++) {
            const int s = ((c0 + 4 * ks + m16) & 15) * 8;       // swizzled slot (elems)
            bf16x8 af[4], bfr[4];
#pragma unroll
            for (int i = 0; i < 4; i++) af[i]  = *(const bf16x8*)(Asr + i * 2048 + s);
#pragma unroll
            for (int j = 0; j < 4; j++) bfr[j] = *(const bf16x8*)(Bsr + j * 2048 + s);
#pragma unroll
            for (int i = 0; i < 4; i++)
#pragma unroll
                for (int j = 0; j < 4; j++)
                    acc[i][j] = __builtin_amdgcn_mfma_f32_16x16x32_bf16(af[i], bfr[j], acc[i][j], 0, 0, 0);
        }
        __syncthreads();
    }

    // epilogue: per-wave LDS transpose -> coalesced f32x4 stores (256 B segments)
    float* Tw = (float*)smem + wave * 1088;
    const int rq = (lane >> 4) * 4;
#pragma unroll
    for (int i = 0; i < 4; i++) {
#pragma unroll
        for (int j = 0; j < 4; j++)
#pragma unroll
            for (int r = 0; r < 4; r++)
                Tw[(rq + r) * 68 + j * 16 + m16] = acc[i][j][r];
        __syncthreads();
#pragma unroll
        for (int s = 0; s < 4; s++) {
            int row = (lane >> 4) + 4 * s;
            f32x4 v = *(const f32x4*)(Tw + row * 68 + (m16 << 2));
            long grow = mBase + waveM + i * 16 + row;
            int  gcol = nBase + waveN + (m16 << 2);
            *(f32x4*)(Out + grow * D_MODEL + gcol) = v;
        }
        __syncthreads();
    }
}

extern "C" void kernel_launch(void* const* d_in, const int* in_sizes, int n_in,
                              void* d_out, int out_size, void* d_ws, size_t ws_size,
                              hipStream_t stream) {
    (void)in_sizes; (void)n_in; (void)out_size;
    const float* x     = (const float*)d_in[0];
    const float* lut_g = (const float*)d_in[1];
    const float* lut_u = (const float*)d_in[2];
    const float* lut_d = (const float*)d_in[3];
    const int*   wk_g  = (const int*)d_in[4];
    const int*   wk_u  = (const int*)d_in[5];
    const int*   wk_d  = (const int*)d_in[6];
    const float* sl_g  = (const float*)d_in[7];
    const float* sr_g  = (const float*)d_in[8];
    const float* sl_u  = (const float*)d_in[9];
    const float* sr_u  = (const float*)d_in[10];
    const float* sl_d  = (const float*)d_in[11];
    const float* sr_d  = (const float*)d_in[12];

    char* ws = (char*)d_ws;
    bf16* xb = (bf16*)(ws);                                   // 16 MB
    bf16* Wg = (bf16*)(ws + (size_t)16 * 1024 * 1024);        // 32 MB
    bf16* Wu = (bf16*)(ws + (size_t)48 * 1024 * 1024);        // 32 MB
    bf16* G  = (bf16*)(ws + (size_t)80 * 1024 * 1024);        // 64 MB
    const bool sepWd = ws_size >= (size_t)176 * 1024 * 1024;
    bf16* Wd = sepWd ? (bf16*)(ws + (size_t)144 * 1024 * 1024) : Wg;
    float* out = (float*)d_out;

    prep_kernel<<<dim3(sepWd ? 28672 : 20480), 256, 0, stream>>>(
        x, xb, wk_g, lut_g, sl_g, sr_g, Wg, wk_u, lut_u, sl_u, sr_u, Wu,
        wk_d, lut_d, sl_d, sr_d, sepWd ? Wd : nullptr);

    gemm_gateup<<<dim3(D_FF / 128, NTOK / 128), 256, 0, stream>>>(xb, Wg, Wu, G);

    if (!sepWd)
        dequant_kernel<<<dim3(D_MODEL * D_FF / 2048), 256, 0, stream>>>(wk_d, lut_d, sl_d, sr_d, Wd, 13);

    gemm_down<<<dim3(D_MODEL / 128, NTOK / 128), 256, 0, stream>>>(G, Wd, out);
}